// Round 1
// baseline (1025.895 us; speedup 1.0000x reference)
//
#include <hip/hip_runtime.h>
#include <math.h>

#define NV 32000
#define NE 1024
#define NH 1024
#define NS 1024
#define NB 64

// d_out layout (floats): output(B,V) | context(B,H) | hidden(1,B,H) | attn(B,1,S)
#define OUT_CTX   (NB*NV)
#define OUT_HID   (NB*NV + NB*NH)
#define OUT_ATTN  (NB*NV + 2*NB*NH)

// workspace layout (floats)
#define WS_X0   0                         // B x 2048
#define WS_PGI  (NB*2048)                 // 8 x 3072 x B
#define WS_PGH  (WS_PGI + 8*3072*NB)      // 8 x 3072 x B
#define WS_E    (WS_PGH + 8*3072*NB)      // B x S   (energies, [b][s])
#define WS_PCTX (WS_E + NB*NS)            // 16 x B x H

// ---------------- embedding + concat -> x0 (B x 2048) ----------------
__global__ void k_embed(const int* __restrict__ wi, const float* __restrict__ lctx,
                        const float* __restrict__ emb, float* __restrict__ ws) {
    int b = blockIdx.x, t = threadIdx.x;           // 64 blocks x 512 threads
    float4* dst = (float4*)(ws + WS_X0 + (long)b*2048);
    if (t < 256) {
        long row = wi[b];
        dst[t] = ((const float4*)(emb + row*NE))[t];
    } else {
        dst[t] = ((const float4*)(lctx + (long)b*NH))[t - 256];
    }
}

// ---------------- GRU GEMM partials ----------------
// wave computes 8 n-columns over a 384-wide virtual-K chunk (covers gi K=2048 then gh K=1024)
__global__ void k_gru_gemm(const float* __restrict__ w_ih, const float* __restrict__ w_hh,
                           const float* __restrict__ lhid, float* __restrict__ ws) {
    int wave = blockIdx.x*4 + (threadIdx.x >> 6);   // 3072 waves
    int lane = threadIdx.x & 63;                    // lane = b
    int ng = wave >> 3, c = wave & 7;
    int n0 = ng*8;
    int lo = c*384, hi = lo + 384;
    float acc_i[8] = {0,0,0,0,0,0,0,0};
    float acc_h[8] = {0,0,0,0,0,0,0,0};

    const float* x0 = ws + WS_X0 + (long)lane*2048;
    int gi_hi = hi < 2048 ? hi : 2048;
    for (int k = lo; k < gi_hi; k += 4) {
        float4 x4 = *(const float4*)(x0 + k);
        #pragma unroll
        for (int j = 0; j < 8; j++) {
            float4 w4 = *(const float4*)(w_ih + (long)(n0+j)*2048 + k);
            acc_i[j] += x4.x*w4.x + x4.y*w4.y + x4.z*w4.z + x4.w*w4.w;
        }
    }
    int gh_lo = lo > 2048 ? lo - 2048 : 0;
    int gh_hi = hi > 2048 ? hi - 2048 : 0;
    const float* hrow = lhid + (long)lane*NH;
    for (int k = gh_lo; k < gh_hi; k += 4) {
        float4 x4 = *(const float4*)(hrow + k);
        #pragma unroll
        for (int j = 0; j < 8; j++) {
            float4 w4 = *(const float4*)(w_hh + (long)(n0+j)*1024 + k);
            acc_h[j] += x4.x*w4.x + x4.y*w4.y + x4.z*w4.z + x4.w*w4.w;
        }
    }
    #pragma unroll
    for (int j = 0; j < 8; j++) {
        ws[WS_PGI + ((long)c*3072 + n0 + j)*64 + lane] = acc_i[j];
        ws[WS_PGH + ((long)c*3072 + n0 + j)*64 + lane] = acc_h[j];
    }
}

// ---------------- GRU gates ----------------
__global__ void k_gates(const float* __restrict__ ws, const float* __restrict__ b_ih,
                        const float* __restrict__ b_hh, const float* __restrict__ lhid,
                        float* __restrict__ out) {
    int g = blockIdx.x*256 + threadIdx.x;  // 65536 threads
    int b = g & 63, i = g >> 6;
    float gir=0.f, giz=0.f, gin=0.f, ghr=0.f, ghz=0.f, ghn=0.f;
    #pragma unroll
    for (int c = 0; c < 8; c++) {
        long base = (long)c*3072*64;
        gir += ws[WS_PGI + base + ((long)(0*NH + i))*64 + b];
        giz += ws[WS_PGI + base + ((long)(1*NH + i))*64 + b];
        gin += ws[WS_PGI + base + ((long)(2*NH + i))*64 + b];
        ghr += ws[WS_PGH + base + ((long)(0*NH + i))*64 + b];
        ghz += ws[WS_PGH + base + ((long)(1*NH + i))*64 + b];
        ghn += ws[WS_PGH + base + ((long)(2*NH + i))*64 + b];
    }
    gir += b_ih[i];        ghr += b_hh[i];
    giz += b_ih[NH + i];   ghz += b_hh[NH + i];
    gin += b_ih[2*NH + i]; ghn += b_hh[2*NH + i];
    float r = 1.f / (1.f + expf(-(gir + ghr)));
    float z = 1.f / (1.f + expf(-(giz + ghz)));
    float n = tanhf(gin + r*ghn);
    float hp = lhid[(long)b*NH + i];
    out[OUT_HID + (long)b*NH + i] = (1.f - z)*n + z*hp;
}

// ---------------- attention energies: e[b][s] = dot(h[b], enc[s][b]) ----------------
__global__ void k_energy(const float* __restrict__ enc, const float* __restrict__ out,
                         float* __restrict__ ws) {
    int wave = blockIdx.x*4 + (threadIdx.x >> 6);   // 65536 waves
    int lane = threadIdx.x & 63;
    int s = wave >> 6, b = wave & 63;
    const float4* er = (const float4*)(enc + ((long)s*NB + b)*NH);
    const float4* hr = (const float4*)(out + OUT_HID + (long)b*NH);
    float acc = 0.f;
    #pragma unroll
    for (int it = 0; it < 4; it++) {
        float4 e4 = er[it*64 + lane];
        float4 h4 = hr[it*64 + lane];
        acc += e4.x*h4.x + e4.y*h4.y + e4.z*h4.z + e4.w*h4.w;
    }
    #pragma unroll
    for (int m = 32; m > 0; m >>= 1) acc += __shfl_xor(acc, m);
    if (lane == 0) ws[WS_E + (long)b*NS + s] = acc;
}

// ---------------- softmax over s (per b) -> attn output [b][s] ----------------
__global__ void k_softmax(const float* __restrict__ ws, float* __restrict__ out) {
    int b = blockIdx.x, t = threadIdx.x;   // 64 x 256
    __shared__ float red[256];
    float4 v = ((const float4*)(ws + WS_E + (long)b*NS))[t];
    float m = fmaxf(fmaxf(v.x, v.y), fmaxf(v.z, v.w));
    red[t] = m; __syncthreads();
    for (int o = 128; o > 0; o >>= 1) { if (t < o) red[t] = fmaxf(red[t], red[t+o]); __syncthreads(); }
    float M = red[0]; __syncthreads();
    float4 ex = make_float4(expf(v.x-M), expf(v.y-M), expf(v.z-M), expf(v.w-M));
    red[t] = ex.x + ex.y + ex.z + ex.w; __syncthreads();
    for (int o = 128; o > 0; o >>= 1) { if (t < o) red[t] += red[t+o]; __syncthreads(); }
    float inv = 1.f / red[0];
    ((float4*)(out + OUT_ATTN + (long)b*NS))[t] =
        make_float4(ex.x*inv, ex.y*inv, ex.z*inv, ex.w*inv);
}

// ---------------- context partials: 64 b x 16 s-chunks ----------------
__global__ void k_ctx_partial(const float* __restrict__ enc, const float* __restrict__ out,
                              float* __restrict__ ws) {
    int b = blockIdx.x >> 4, c = blockIdx.x & 15;  // 1024 blocks x 256
    int h0 = threadIdx.x * 4;
    const float* w = out + OUT_ATTN + (long)b*NS + c*64;
    float4 acc = make_float4(0.f,0.f,0.f,0.f);
    for (int si = 0; si < 64; si++) {
        float wv = w[si];
        float4 e4 = *(const float4*)(enc + ((long)(c*64+si)*NB + b)*NH + h0);
        acc.x += wv*e4.x; acc.y += wv*e4.y; acc.z += wv*e4.z; acc.w += wv*e4.w;
    }
    *(float4*)(ws + WS_PCTX + ((long)c*NB + b)*NH + h0) = acc;
}

__global__ void k_ctx_reduce(const float* __restrict__ ws, float* __restrict__ out) {
    int g = blockIdx.x*256 + threadIdx.x;  // 64 x 256 -> one float4 per thread
    int b = g >> 8, h0 = (g & 255)*4;
    float4 acc = make_float4(0.f,0.f,0.f,0.f);
    #pragma unroll
    for (int c = 0; c < 16; c++) {
        float4 p = *(const float4*)(ws + WS_PCTX + ((long)c*NB + b)*NH + h0);
        acc.x += p.x; acc.y += p.y; acc.z += p.z; acc.w += p.w;
    }
    *(float4*)(out + OUT_CTX + (long)b*NH + h0) = acc;
}

// ---------------- logits: wave = 16 vocab rows, lane = b ----------------
__global__ void k_logits(const float* __restrict__ oW, const float* __restrict__ ob,
                         float* __restrict__ out) {
    int wave = blockIdx.x*4 + (threadIdx.x >> 6);   // 2000 waves
    int lane = threadIdx.x & 63;
    int v0 = wave * 16;
    float acc[16];
    #pragma unroll
    for (int j = 0; j < 16; j++) acc[j] = 0.f;
    const float* h  = out + OUT_HID + (long)lane*NH;
    const float* cx = out + OUT_CTX + (long)lane*NH;
    for (int k = 0; k < 1024; k += 4) {
        float4 x4 = *(const float4*)(h + k);
        #pragma unroll
        for (int j = 0; j < 16; j++) {
            float4 w4 = *(const float4*)(oW + (long)(v0+j)*2048 + k);
            acc[j] += x4.x*w4.x + x4.y*w4.y + x4.z*w4.z + x4.w*w4.w;
        }
    }
    for (int k = 0; k < 1024; k += 4) {
        float4 x4 = *(const float4*)(cx + k);
        #pragma unroll
        for (int j = 0; j < 16; j++) {
            float4 w4 = *(const float4*)(oW + (long)(v0+j)*2048 + 1024 + k);
            acc[j] += x4.x*w4.x + x4.y*w4.y + x4.z*w4.z + x4.w*w4.w;
        }
    }
    #pragma unroll
    for (int j = 0; j < 16; j++) acc[j] += ob[v0 + j];
    float* orow = out + (long)lane*NV + v0;
    #pragma unroll
    for (int q = 0; q < 4; q++)
        *(float4*)(orow + q*4) = make_float4(acc[q*4+0], acc[q*4+1], acc[q*4+2], acc[q*4+3]);
}

// ---------------- in-place log_softmax per b row ----------------
__global__ void k_logsoftmax(float* __restrict__ out) {
    int b = blockIdx.x, t = threadIdx.x;  // 64 x 256
    float* row = out + (long)b*NV;
    __shared__ float red[256];
    float m = -1e30f;
    for (int i = t*4; i < NV; i += 1024) {
        float4 v = *(const float4*)(row + i);
        m = fmaxf(m, fmaxf(fmaxf(v.x, v.y), fmaxf(v.z, v.w)));
    }
    red[t] = m; __syncthreads();
    for (int o = 128; o > 0; o >>= 1) { if (t < o) red[t] = fmaxf(red[t], red[t+o]); __syncthreads(); }
    float M = red[0]; __syncthreads();
    float ss = 0.f;
    for (int i = t*4; i < NV; i += 1024) {
        float4 v = *(const float4*)(row + i);
        ss += expf(v.x-M) + expf(v.y-M) + expf(v.z-M) + expf(v.w-M);
    }
    red[t] = ss; __syncthreads();
    for (int o = 128; o > 0; o >>= 1) { if (t < o) red[t] += red[t+o]; __syncthreads(); }
    float lse = M + logf(red[0]);
    for (int i = t*4; i < NV; i += 1024) {
        float4 v = *(const float4*)(row + i);
        *(float4*)(row + i) = make_float4(v.x-lse, v.y-lse, v.z-lse, v.w-lse);
    }
}

extern "C" void kernel_launch(void* const* d_in, const int* in_sizes, int n_in,
                              void* d_out, int out_size, void* d_ws, size_t ws_size,
                              hipStream_t stream) {
    const int*   wi   = (const int*)d_in[0];
    const float* lctx = (const float*)d_in[1];
    const float* lhid = (const float*)d_in[2];
    const float* enc  = (const float*)d_in[3];
    const float* emb  = (const float*)d_in[4];
    const float* w_ih = (const float*)d_in[5];
    const float* w_hh = (const float*)d_in[6];
    const float* b_ih = (const float*)d_in[7];
    const float* b_hh = (const float*)d_in[8];
    const float* oW   = (const float*)d_in[9];
    const float* ob   = (const float*)d_in[10];
    float* out = (float*)d_out;
    float* ws  = (float*)d_ws;

    hipLaunchKernelGGL(k_embed,      dim3(64),    dim3(512), 0, stream, wi, lctx, emb, ws);
    hipLaunchKernelGGL(k_gru_gemm,   dim3(768),   dim3(256), 0, stream, w_ih, w_hh, lhid, ws);
    hipLaunchKernelGGL(k_gates,      dim3(256),   dim3(256), 0, stream, ws, b_ih, b_hh, lhid, out);
    hipLaunchKernelGGL(k_energy,     dim3(16384), dim3(256), 0, stream, enc, out, ws);
    hipLaunchKernelGGL(k_softmax,    dim3(64),    dim3(256), 0, stream, ws, out);
    hipLaunchKernelGGL(k_ctx_partial,dim3(1024),  dim3(256), 0, stream, enc, out, ws);
    hipLaunchKernelGGL(k_ctx_reduce, dim3(64),    dim3(256), 0, stream, ws, out);
    hipLaunchKernelGGL(k_logits,     dim3(500),   dim3(256), 0, stream, oW, ob, out);
    hipLaunchKernelGGL(k_logsoftmax, dim3(64),    dim3(256), 0, stream, out);
}

// Round 2
// 250.900 us; speedup vs baseline: 4.0889x; 4.0889x over previous
//
#include <hip/hip_runtime.h>
#include <math.h>

#define NV 32000
#define NE 1024
#define NH 1024
#define NS 1024
#define NB 64

typedef __attribute__((ext_vector_type(4))) float f32x4;
typedef __attribute__((ext_vector_type(8))) short bf16x8;

// d_out layout (floats): output(B,V) | context(B,H) | hidden(1,B,H) | attn(B,1,S)
#define OUT_CTX   (NB*NV)
#define OUT_HID   (NB*NV + NB*NH)
#define OUT_ATTN  (NB*NV + 2*NB*NH)

// workspace layout (floats)
#define WS_XA   0                          // ushort[64][2048] x0 bf16  -> 65536 floats
#define WS_HA   (WS_XA + 65536)            // ushort[64][1024] h_prev bf16 -> 32768 floats
#define WS_PG   (WS_HA + 32768)            // f32 [6][3072][64] GRU partials
#define WS_E    (WS_PG + 6*3072*64)        // f32 [64][1024] energies
#define WS_PCTX (WS_E + NB*NS)             // f32 [16][64][1024] context partials
#define WS_LA   (WS_PCTX + 16*64*1024)     // ushort[64][2048] concat(h,ctx) bf16

__device__ inline unsigned short f2bf(float f) {
    unsigned u = __builtin_bit_cast(unsigned, f);
    u += 0x7fffu + ((u >> 16) & 1u);   // RNE
    return (unsigned short)(u >> 16);
}

__device__ inline bf16x8 cvt8(float4 a, float4 b) {
    bf16x8 r;
    r[0] = (short)f2bf(a.x); r[1] = (short)f2bf(a.y);
    r[2] = (short)f2bf(a.z); r[3] = (short)f2bf(a.w);
    r[4] = (short)f2bf(b.x); r[5] = (short)f2bf(b.y);
    r[6] = (short)f2bf(b.z); r[7] = (short)f2bf(b.w);
    return r;
}

__device__ inline void store_bf4(unsigned short* p, float4 v) {
    ushort4 u = make_ushort4(f2bf(v.x), f2bf(v.y), f2bf(v.z), f2bf(v.w));
    *(ushort4*)p = u;
}

// ---------------- prep: x0 = concat(emb, lctx) -> bf16; h_prev -> bf16 ----------------
__global__ void k_prep(const int* __restrict__ wi, const float* __restrict__ lctx,
                       const float* __restrict__ lhid, const float* __restrict__ emb,
                       float* __restrict__ ws) {
    int b = blockIdx.x, t = threadIdx.x;           // 64 x 256
    unsigned short* XA = (unsigned short*)(ws + WS_XA);
    unsigned short* HA = (unsigned short*)(ws + WS_HA);
    long row = wi[b];
    float4 e4 = ((const float4*)(emb + row*NE))[t];
    float4 c4 = ((const float4*)(lctx + (long)b*NH))[t];
    float4 h4 = ((const float4*)(lhid + (long)b*NH))[t];
    store_bf4(XA + (long)b*2048 + t*4,        e4);
    store_bf4(XA + (long)b*2048 + 1024 + t*4, c4);
    store_bf4(HA + (long)b*1024 + t*4,        h4);
}

// ---------------- GRU GEMM via MFMA: partials [6][3072][64] ----------------
// chunk c<4: gi over w_ih K=[c*512,+512); c>=4: gh over w_hh K=[(c-4)*512,+512)
__global__ void __launch_bounds__(256) k_gru_mfma(const float* __restrict__ w_ih,
                                                  const float* __restrict__ w_hh,
                                                  float* __restrict__ ws) {
    int wave = blockIdx.x*4 + (threadIdx.x >> 6);   // 1152 waves
    int lane = threadIdx.x & 63;
    int c = wave % 6, ntile = wave / 6;
    int n0 = ntile * 16;
    int col = lane & 15, kg = lane >> 4;
    const unsigned short* XA = (const unsigned short*)(ws + WS_XA);
    const unsigned short* HA = (const unsigned short*)(ws + WS_HA);
    const float* Wp; const unsigned short* Ap; int ld, kbase;
    if (c < 4) { Wp = w_ih; Ap = XA; ld = 2048; kbase = c*512; }
    else       { Wp = w_hh; Ap = HA; ld = 1024; kbase = (c-4)*512; }
    const float* wrow = Wp + (long)(n0 + col)*ld + kbase + kg*8;
    f32x4 acc[4];
    #pragma unroll
    for (int m = 0; m < 4; m++) acc[m] = (f32x4){0.f,0.f,0.f,0.f};
    for (int k0 = 0; k0 < 512; k0 += 32) {
        float4 wa = *(const float4*)(wrow + k0);
        float4 wb = *(const float4*)(wrow + k0 + 4);
        bf16x8 bf = cvt8(wa, wb);
        #pragma unroll
        for (int m = 0; m < 4; m++) {
            bf16x8 af = *(const bf16x8*)(Ap + (long)(m*16 + col)*ld + kbase + k0 + kg*8);
            acc[m] = __builtin_amdgcn_mfma_f32_16x16x32_bf16(af, bf, acc[m], 0, 0, 0);
        }
    }
    float* pg = ws + WS_PG + ((long)c*3072 + n0 + col)*64;
    #pragma unroll
    for (int m = 0; m < 4; m++)
        #pragma unroll
        for (int j = 0; j < 4; j++)
            pg[m*16 + kg*4 + j] = acc[m][j];
}

// ---------------- GRU gates ----------------
__global__ void k_gates(const float* __restrict__ wsc, const float* __restrict__ b_ih,
                        const float* __restrict__ b_hh, const float* __restrict__ lhid,
                        float* __restrict__ out, float* __restrict__ ws) {
    int g = blockIdx.x*256 + threadIdx.x;  // 65536 threads
    int b = g & 63, i = g >> 6;
    float gir=0.f, giz=0.f, gin=0.f, ghr=0.f, ghz=0.f, ghn=0.f;
    #pragma unroll
    for (int c = 0; c < 4; c++) {
        long base = WS_PG + (long)c*3072*64;
        gir += wsc[base + ((long)(0*NH + i))*64 + b];
        giz += wsc[base + ((long)(1*NH + i))*64 + b];
        gin += wsc[base + ((long)(2*NH + i))*64 + b];
    }
    #pragma unroll
    for (int c = 4; c < 6; c++) {
        long base = WS_PG + (long)c*3072*64;
        ghr += wsc[base + ((long)(0*NH + i))*64 + b];
        ghz += wsc[base + ((long)(1*NH + i))*64 + b];
        ghn += wsc[base + ((long)(2*NH + i))*64 + b];
    }
    gir += b_ih[i];        ghr += b_hh[i];
    giz += b_ih[NH + i];   ghz += b_hh[NH + i];
    gin += b_ih[2*NH + i]; ghn += b_hh[2*NH + i];
    float r = 1.f / (1.f + expf(-(gir + ghr)));
    float z = 1.f / (1.f + expf(-(giz + ghz)));
    float n = tanhf(gin + r*ghn);
    float hp = lhid[(long)b*NH + i];
    float h = (1.f - z)*n + z*hp;
    out[OUT_HID + (long)b*NH + i] = h;
    ((unsigned short*)(ws + WS_LA))[(long)b*2048 + i] = f2bf(h);
}

// ---------------- attention energies: e[b][s] = dot(h[b], enc[s][b]) ----------------
__global__ void k_energy(const float* __restrict__ enc, const float* __restrict__ out,
                         float* __restrict__ ws) {
    int wave = blockIdx.x*4 + (threadIdx.x >> 6);   // 65536 waves
    int lane = threadIdx.x & 63;
    int s = wave >> 6, b = wave & 63;
    const float4* er = (const float4*)(enc + ((long)s*NB + b)*NH);
    const float4* hr = (const float4*)(out + OUT_HID + (long)b*NH);
    float acc = 0.f;
    #pragma unroll
    for (int it = 0; it < 4; it++) {
        float4 e4 = er[it*64 + lane];
        float4 h4 = hr[it*64 + lane];
        acc += e4.x*h4.x + e4.y*h4.y + e4.z*h4.z + e4.w*h4.w;
    }
    #pragma unroll
    for (int m = 32; m > 0; m >>= 1) acc += __shfl_xor(acc, m);
    if (lane == 0) ws[WS_E + (long)b*NS + s] = acc;
}

// ---------------- softmax over s (per b) -> attn output [b][s] ----------------
__global__ void k_softmax(const float* __restrict__ ws, float* __restrict__ out) {
    int b = blockIdx.x, t = threadIdx.x;   // 64 x 256
    __shared__ float red[256];
    float4 v = ((const float4*)(ws + WS_E + (long)b*NS))[t];
    float m = fmaxf(fmaxf(v.x, v.y), fmaxf(v.z, v.w));
    red[t] = m; __syncthreads();
    for (int o = 128; o > 0; o >>= 1) { if (t < o) red[t] = fmaxf(red[t], red[t+o]); __syncthreads(); }
    float M = red[0]; __syncthreads();
    float4 ex = make_float4(expf(v.x-M), expf(v.y-M), expf(v.z-M), expf(v.w-M));
    red[t] = ex.x + ex.y + ex.z + ex.w; __syncthreads();
    for (int o = 128; o > 0; o >>= 1) { if (t < o) red[t] += red[t+o]; __syncthreads(); }
    float inv = 1.f / red[0];
    ((float4*)(out + OUT_ATTN + (long)b*NS))[t] =
        make_float4(ex.x*inv, ex.y*inv, ex.z*inv, ex.w*inv);
}

// ---------------- context partials: 64 b x 16 s-chunks ----------------
__global__ void k_ctx_partial(const float* __restrict__ enc, const float* __restrict__ out,
                              float* __restrict__ ws) {
    int b = blockIdx.x >> 4, c = blockIdx.x & 15;  // 1024 blocks x 256
    int h0 = threadIdx.x * 4;
    const float* w = out + OUT_ATTN + (long)b*NS + c*64;
    float4 acc = make_float4(0.f,0.f,0.f,0.f);
    for (int si = 0; si < 64; si++) {
        float wv = w[si];
        float4 e4 = *(const float4*)(enc + ((long)(c*64+si)*NB + b)*NH + h0);
        acc.x += wv*e4.x; acc.y += wv*e4.y; acc.z += wv*e4.z; acc.w += wv*e4.w;
    }
    *(float4*)(ws + WS_PCTX + ((long)c*NB + b)*NH + h0) = acc;
}

__global__ void k_ctx_reduce(const float* __restrict__ wsc, float* __restrict__ out,
                             float* __restrict__ ws) {
    int g = blockIdx.x*256 + threadIdx.x;  // 64 x 256 -> one float4 per thread
    int b = g >> 8, h0 = (g & 255)*4;
    float4 acc = make_float4(0.f,0.f,0.f,0.f);
    #pragma unroll
    for (int c = 0; c < 16; c++) {
        float4 p = *(const float4*)(wsc + WS_PCTX + ((long)c*NB + b)*NH + h0);
        acc.x += p.x; acc.y += p.y; acc.z += p.z; acc.w += p.w;
    }
    *(float4*)(out + OUT_CTX + (long)b*NH + h0) = acc;
    store_bf4((unsigned short*)(ws + WS_LA) + (long)b*2048 + 1024 + h0, acc);
}

// ---------------- logits via MFMA: wave = 16 vocab cols x all 64 b ----------------
__global__ void __launch_bounds__(256) k_logits_mfma(const float* __restrict__ oW,
                                                     const float* __restrict__ ob,
                                                     const float* __restrict__ wsc,
                                                     float* __restrict__ out) {
    int wave = blockIdx.x*4 + (threadIdx.x >> 6);   // 2000 waves
    int lane = threadIdx.x & 63;
    int v0 = wave * 16;
    int col = lane & 15, kg = lane >> 4;
    const unsigned short* LA = (const unsigned short*)(wsc + WS_LA);
    const float* wrow = oW + (long)(v0 + col)*2048 + kg*8;
    f32x4 acc[4];
    #pragma unroll
    for (int m = 0; m < 4; m++) acc[m] = (f32x4){0.f,0.f,0.f,0.f};
    #pragma unroll 2
    for (int k0 = 0; k0 < 2048; k0 += 32) {
        float4 wa = *(const float4*)(wrow + k0);
        float4 wb = *(const float4*)(wrow + k0 + 4);
        bf16x8 bf = cvt8(wa, wb);
        #pragma unroll
        for (int m = 0; m < 4; m++) {
            bf16x8 af = *(const bf16x8*)(LA + (long)(m*16 + col)*2048 + k0 + kg*8);
            acc[m] = __builtin_amdgcn_mfma_f32_16x16x32_bf16(af, bf, acc[m], 0, 0, 0);
        }
    }
    float bias = ob[v0 + col];
    #pragma unroll
    for (int m = 0; m < 4; m++)
        #pragma unroll
        for (int j = 0; j < 4; j++)
            out[(long)(m*16 + kg*4 + j)*NV + v0 + col] = acc[m][j] + bias;
}

// ---------------- in-place log_softmax per b row ----------------
__global__ void k_logsoftmax(float* __restrict__ out) {
    int b = blockIdx.x, t = threadIdx.x;  // 64 x 256
    float* row = out + (long)b*NV;
    __shared__ float red[256];
    float m = -1e30f;
    for (int i = t*4; i < NV; i += 1024) {
        float4 v = *(const float4*)(row + i);
        m = fmaxf(m, fmaxf(fmaxf(v.x, v.y), fmaxf(v.z, v.w)));
    }
    red[t] = m; __syncthreads();
    for (int o = 128; o > 0; o >>= 1) { if (t < o) red[t] = fmaxf(red[t], red[t+o]); __syncthreads(); }
    float M = red[0]; __syncthreads();
    float ss = 0.f;
    for (int i = t*4; i < NV; i += 1024) {
        float4 v = *(const float4*)(row + i);
        ss += expf(v.x-M) + expf(v.y-M) + expf(v.z-M) + expf(v.w-M);
    }
    red[t] = ss; __syncthreads();
    for (int o = 128; o > 0; o >>= 1) { if (t < o) red[t] += red[t+o]; __syncthreads(); }
    float lse = M + logf(red[0]);
    for (int i = t*4; i < NV; i += 1024) {
        float4 v = *(const float4*)(row + i);
        *(float4*)(row + i) = make_float4(v.x-lse, v.y-lse, v.z-lse, v.w-lse);
    }
}

extern "C" void kernel_launch(void* const* d_in, const int* in_sizes, int n_in,
                              void* d_out, int out_size, void* d_ws, size_t ws_size,
                              hipStream_t stream) {
    const int*   wi   = (const int*)d_in[0];
    const float* lctx = (const float*)d_in[1];
    const float* lhid = (const float*)d_in[2];
    const float* enc  = (const float*)d_in[3];
    const float* emb  = (const float*)d_in[4];
    const float* w_ih = (const float*)d_in[5];
    const float* w_hh = (const float*)d_in[6];
    const float* b_ih = (const float*)d_in[7];
    const float* b_hh = (const float*)d_in[8];
    const float* oW   = (const float*)d_in[9];
    const float* ob   = (const float*)d_in[10];
    float* out = (float*)d_out;
    float* ws  = (float*)d_ws;

    hipLaunchKernelGGL(k_prep,       dim3(64),    dim3(256), 0, stream, wi, lctx, lhid, emb, ws);
    hipLaunchKernelGGL(k_gru_mfma,   dim3(288),   dim3(256), 0, stream, w_ih, w_hh, ws);
    hipLaunchKernelGGL(k_gates,      dim3(256),   dim3(256), 0, stream, ws, b_ih, b_hh, lhid, out, ws);
    hipLaunchKernelGGL(k_energy,     dim3(16384), dim3(256), 0, stream, enc, out, ws);
    hipLaunchKernelGGL(k_softmax,    dim3(64),    dim3(256), 0, stream, ws, out);
    hipLaunchKernelGGL(k_ctx_partial,dim3(1024),  dim3(256), 0, stream, enc, out, ws);
    hipLaunchKernelGGL(k_ctx_reduce, dim3(64),    dim3(256), 0, stream, ws, out, ws);
    hipLaunchKernelGGL(k_logits_mfma,dim3(500),   dim3(256), 0, stream, oW, ob, ws, out);
    hipLaunchKernelGGL(k_logsoftmax, dim3(64),    dim3(256), 0, stream, out);
}

// Round 3
// 244.462 us; speedup vs baseline: 4.1965x; 1.0263x over previous
//
#include <hip/hip_runtime.h>
#include <math.h>

#define NV 32000
#define NE 1024
#define NH 1024
#define NS 1024
#define NB 64

typedef __attribute__((ext_vector_type(4))) float f32x4;
typedef __attribute__((ext_vector_type(8))) short bf16x8;

// d_out layout (floats): output(B,V) | context(B,H) | hidden(1,B,H) | attn(B,1,S)
#define OUT_CTX   (NB*NV)
#define OUT_HID   (NB*NV + NB*NH)
#define OUT_ATTN  (NB*NV + 2*NB*NH)

// workspace layout (float offsets)
#define WS_XA   0                          // ushort[64][2048] x0 bf16
#define WS_HA   (WS_XA + 65536)            // ushort[64][1024] h_prev bf16
#define WS_PG   (WS_HA + 32768)            // f32 [6][3072][64] GRU partials
#define WS_E    (WS_PG + 6*3072*64)        // f32 [64][1024] raw energies
#define WS_PCTX (WS_E + NB*NS)             // f32 [64][64][1024] attn ctx partials (b, g, h)
#define WS_ML   (WS_PCTX + 64*64*1024)     // f32 [64][64][2]  (m, l) per (b, g)
#define WS_LA   (WS_ML + 8192)             // ushort[64][2048] concat(h,ctx) bf16
#define WS_P    (WS_LA + 65536)            // f32 [2][64][32000] logits partials

__device__ inline unsigned short f2bf(float f) {
    unsigned u = __builtin_bit_cast(unsigned, f);
    u += 0x7fffu + ((u >> 16) & 1u);   // RNE
    return (unsigned short)(u >> 16);
}

__device__ inline bf16x8 cvt8(float4 a, float4 b) {
    bf16x8 r;
    r[0] = (short)f2bf(a.x); r[1] = (short)f2bf(a.y);
    r[2] = (short)f2bf(a.z); r[3] = (short)f2bf(a.w);
    r[4] = (short)f2bf(b.x); r[5] = (short)f2bf(b.y);
    r[6] = (short)f2bf(b.z); r[7] = (short)f2bf(b.w);
    return r;
}

__device__ inline void store_bf4(unsigned short* p, float4 v) {
    ushort4 u = make_ushort4(f2bf(v.x), f2bf(v.y), f2bf(v.z), f2bf(v.w));
    *(ushort4*)p = u;
}

// ---------------- prep: x0 = concat(emb, lctx) -> bf16; h_prev -> bf16 ----------------
__global__ void k_prep(const int* __restrict__ wi, const float* __restrict__ lctx,
                       const float* __restrict__ lhid, const float* __restrict__ emb,
                       float* __restrict__ ws) {
    int b = blockIdx.x, t = threadIdx.x;           // 64 x 256
    unsigned short* XA = (unsigned short*)(ws + WS_XA);
    unsigned short* HA = (unsigned short*)(ws + WS_HA);
    long row = wi[b];
    float4 e4 = ((const float4*)(emb + row*NE))[t];
    float4 c4 = ((const float4*)(lctx + (long)b*NH))[t];
    float4 h4 = ((const float4*)(lhid + (long)b*NH))[t];
    store_bf4(XA + (long)b*2048 + t*4,        e4);
    store_bf4(XA + (long)b*2048 + 1024 + t*4, c4);
    store_bf4(HA + (long)b*1024 + t*4,        h4);
}

// ---------------- GRU GEMM via MFMA: partials [6][3072][64] ----------------
__global__ void __launch_bounds__(256) k_gru_mfma(const float* __restrict__ w_ih,
                                                  const float* __restrict__ w_hh,
                                                  float* __restrict__ ws) {
    int wave = blockIdx.x*4 + (threadIdx.x >> 6);   // 1152 waves
    int lane = threadIdx.x & 63;
    int c = wave % 6, ntile = wave / 6;
    int n0 = ntile * 16;
    int col = lane & 15, kg = lane >> 4;
    const unsigned short* XA = (const unsigned short*)(ws + WS_XA);
    const unsigned short* HA = (const unsigned short*)(ws + WS_HA);
    const float* Wp; const unsigned short* Ap; int ld, kbase;
    if (c < 4) { Wp = w_ih; Ap = XA; ld = 2048; kbase = c*512; }
    else       { Wp = w_hh; Ap = HA; ld = 1024; kbase = (c-4)*512; }
    const float* wrow = Wp + (long)(n0 + col)*ld + kbase + kg*8;
    f32x4 acc[4];
    #pragma unroll
    for (int m = 0; m < 4; m++) acc[m] = (f32x4){0.f,0.f,0.f,0.f};
    for (int k0 = 0; k0 < 512; k0 += 32) {
        float4 wa = *(const float4*)(wrow + k0);
        float4 wb = *(const float4*)(wrow + k0 + 4);
        bf16x8 bf = cvt8(wa, wb);
        #pragma unroll
        for (int m = 0; m < 4; m++) {
            bf16x8 af = *(const bf16x8*)(Ap + (long)(m*16 + col)*ld + kbase + k0 + kg*8);
            acc[m] = __builtin_amdgcn_mfma_f32_16x16x32_bf16(af, bf, acc[m], 0, 0, 0);
        }
    }
    float* pg = ws + WS_PG + ((long)c*3072 + n0 + col)*64;
    #pragma unroll
    for (int m = 0; m < 4; m++)
        #pragma unroll
        for (int j = 0; j < 4; j++)
            pg[m*16 + kg*4 + j] = acc[m][j];
}

// ---------------- GRU gates ----------------
__global__ void k_gates(const float* __restrict__ wsc, const float* __restrict__ b_ih,
                        const float* __restrict__ b_hh, const float* __restrict__ lhid,
                        float* __restrict__ out, float* __restrict__ ws) {
    int g = blockIdx.x*256 + threadIdx.x;  // 65536 threads
    int b = g & 63, i = g >> 6;
    float gir=0.f, giz=0.f, gin=0.f, ghr=0.f, ghz=0.f, ghn=0.f;
    #pragma unroll
    for (int c = 0; c < 4; c++) {
        long base = WS_PG + (long)c*3072*64;
        gir += wsc[base + ((long)(0*NH + i))*64 + b];
        giz += wsc[base + ((long)(1*NH + i))*64 + b];
        gin += wsc[base + ((long)(2*NH + i))*64 + b];
    }
    #pragma unroll
    for (int c = 4; c < 6; c++) {
        long base = WS_PG + (long)c*3072*64;
        ghr += wsc[base + ((long)(0*NH + i))*64 + b];
        ghz += wsc[base + ((long)(1*NH + i))*64 + b];
        ghn += wsc[base + ((long)(2*NH + i))*64 + b];
    }
    gir += b_ih[i];        ghr += b_hh[i];
    giz += b_ih[NH + i];   ghz += b_hh[NH + i];
    gin += b_ih[2*NH + i]; ghn += b_hh[2*NH + i];
    float r = 1.f / (1.f + expf(-(gir + ghr)));
    float z = 1.f / (1.f + expf(-(giz + ghz)));
    float n = tanhf(gin + r*ghn);
    float hp = lhid[(long)b*NH + i];
    float h = (1.f - z)*n + z*hp;
    out[OUT_HID + (long)b*NH + i] = h;
    ((unsigned short*)(ws + WS_LA))[(long)b*2048 + i] = f2bf(h);
}

// ---------------- fused attention: single encoder pass, online softmax ----------------
// wave handles (b, g): 16 s-values s in [g*16, g*16+16); lane covers h = it*256+lane*4
__global__ void __launch_bounds__(256) k_attn(const float* __restrict__ enc,
                                              const float* __restrict__ out,
                                              float* __restrict__ ws) {
    int widx = threadIdx.x >> 6, lane = threadIdx.x & 63;
    int b = blockIdx.x >> 4;                 // 1024 blocks
    int g = (blockIdx.x & 15)*4 + widx;      // 0..63
    float4 h4[4];
    const float4* hr = (const float4*)(out + OUT_HID + (long)b*NH);
    #pragma unroll
    for (int it = 0; it < 4; it++) h4[it] = hr[it*64 + lane];
    float m = -1e30f, l = 0.f;
    float4 ctx[4];
    #pragma unroll
    for (int it = 0; it < 4; it++) ctx[it] = make_float4(0.f,0.f,0.f,0.f);
    for (int si = 0; si < 16; si++) {
        int s = g*16 + si;
        const float4* vp = (const float4*)(enc + ((long)s*NB + b)*NH);
        float4 v4[4];
        float d = 0.f;
        #pragma unroll
        for (int it = 0; it < 4; it++) {
            v4[it] = vp[it*64 + lane];
            d += v4[it].x*h4[it].x + v4[it].y*h4[it].y + v4[it].z*h4[it].z + v4[it].w*h4[it].w;
        }
        #pragma unroll
        for (int o = 32; o > 0; o >>= 1) d += __shfl_xor(d, o);
        if (lane == 0) ws[WS_E + (long)b*NS + s] = d;
        float mnew = fmaxf(m, d);
        float coef = expf(m - mnew);
        float p = expf(d - mnew);
        l = l*coef + p;
        #pragma unroll
        for (int it = 0; it < 4; it++) {
            ctx[it].x = ctx[it].x*coef + p*v4[it].x;
            ctx[it].y = ctx[it].y*coef + p*v4[it].y;
            ctx[it].z = ctx[it].z*coef + p*v4[it].z;
            ctx[it].w = ctx[it].w*coef + p*v4[it].w;
        }
        m = mnew;
    }
    float* pc = ws + WS_PCTX + ((long)b*64 + g)*1024;
    #pragma unroll
    for (int it = 0; it < 4; it++)
        *(float4*)(pc + it*256 + lane*4) = ctx[it];
    if (lane == 0) {
        ws[WS_ML + ((long)b*64 + g)*2]     = m;
        ws[WS_ML + ((long)b*64 + g)*2 + 1] = l;
    }
}

// ---------------- attn reduce: combine partials; emit ctx, attn weights, bf16 LA ----------------
__global__ void k_attn_reduce(const float* __restrict__ wsc, float* __restrict__ out,
                              float* __restrict__ ws) {
    int b = blockIdx.x, t = threadIdx.x;     // 64 x 256
    __shared__ float sm[64], sl[64], sc[64];
    __shared__ float sM, sinvL;
    if (t < 64) {
        sm[t] = wsc[WS_ML + ((long)b*64 + t)*2];
        sl[t] = wsc[WS_ML + ((long)b*64 + t)*2 + 1];
    }
    __syncthreads();
    if (t == 0) {
        float M = -1e30f;
        for (int g = 0; g < 64; g++) M = fmaxf(M, sm[g]);
        float L = 0.f;
        for (int g = 0; g < 64; g++) L += sl[g]*expf(sm[g] - M);
        sM = M; sinvL = 1.f/L;
    }
    __syncthreads();
    float M = sM, invL = sinvL;
    if (t < 64) sc[t] = expf(sm[t] - M);
    __syncthreads();
    // context: h-slice t*4..+4
    float4 acc = make_float4(0.f,0.f,0.f,0.f);
    for (int g = 0; g < 64; g++) {
        float c = sc[g];
        float4 p = *(const float4*)(wsc + WS_PCTX + ((long)b*64 + g)*1024 + t*4);
        acc.x += c*p.x; acc.y += c*p.y; acc.z += c*p.z; acc.w += c*p.w;
    }
    acc.x *= invL; acc.y *= invL; acc.z *= invL; acc.w *= invL;
    *(float4*)(out + OUT_CTX + (long)b*NH + t*4) = acc;
    store_bf4((unsigned short*)(ws + WS_LA) + (long)b*2048 + 1024 + t*4, acc);
    // attn weights: s-slice t*4..+4
    float4 e4 = *(const float4*)(wsc + WS_E + (long)b*NS + t*4);
    *(float4*)(out + OUT_ATTN + (long)b*NS + t*4) =
        make_float4(expf(e4.x-M)*invL, expf(e4.y-M)*invL,
                    expf(e4.z-M)*invL, expf(e4.w-M)*invL);
}

// ---------------- logits via MFMA, split-K: partials [2][64][32000] ----------------
__global__ void __launch_bounds__(256) k_logits_mfma(const float* __restrict__ oW,
                                                     const float* __restrict__ wsc,
                                                     float* __restrict__ ws) {
    int wave = blockIdx.x*4 + (threadIdx.x >> 6);   // 4000 waves
    int lane = threadIdx.x & 63;
    int half = wave & 1, vt = wave >> 1;
    int v0 = vt * 16, kbase = half * 1024;
    int col = lane & 15, kg = lane >> 4;
    const unsigned short* LA = (const unsigned short*)(wsc + WS_LA);
    const float* wrow = oW + (long)(v0 + col)*2048 + kbase + kg*8;
    f32x4 acc[4];
    #pragma unroll
    for (int m = 0; m < 4; m++) acc[m] = (f32x4){0.f,0.f,0.f,0.f};
    #pragma unroll 2
    for (int k0 = 0; k0 < 1024; k0 += 32) {
        float4 wa = *(const float4*)(wrow + k0);
        float4 wb = *(const float4*)(wrow + k0 + 4);
        bf16x8 bf = cvt8(wa, wb);
        #pragma unroll
        for (int m = 0; m < 4; m++) {
            bf16x8 af = *(const bf16x8*)(LA + (long)(m*16 + col)*2048 + kbase + k0 + kg*8);
            acc[m] = __builtin_amdgcn_mfma_f32_16x16x32_bf16(af, bf, acc[m], 0, 0, 0);
        }
    }
    float* P = ws + WS_P + (long)half*(64L*32000);
    #pragma unroll
    for (int m = 0; m < 4; m++)
        #pragma unroll
        for (int j = 0; j < 4; j++)
            P[(long)(m*16 + kg*4 + j)*NV + v0 + col] = acc[m][j];
}

// ---------------- fused: sum partials + bias, then log_softmax ----------------
__global__ void k_logsoftmax(const float* __restrict__ wsc, const float* __restrict__ ob,
                             float* __restrict__ out) {
    int b = blockIdx.x, t = threadIdx.x;  // 64 x 256
    const float* P0 = wsc + WS_P + (long)b*NV;
    const float* P1 = wsc + WS_P + 64L*32000 + (long)b*NV;
    float* row = out + (long)b*NV;
    __shared__ float red[256];
    float m = -1e30f;
    for (int i = t*4; i < NV; i += 1024) {
        float4 a = *(const float4*)(P0 + i);
        float4 c = *(const float4*)(P1 + i);
        float4 bb = *(const float4*)(ob + i);
        float4 v = make_float4(a.x+c.x+bb.x, a.y+c.y+bb.y, a.z+c.z+bb.z, a.w+c.w+bb.w);
        *(float4*)(row + i) = v;
        m = fmaxf(m, fmaxf(fmaxf(v.x, v.y), fmaxf(v.z, v.w)));
    }
    red[t] = m; __syncthreads();
    for (int o = 128; o > 0; o >>= 1) { if (t < o) red[t] = fmaxf(red[t], red[t+o]); __syncthreads(); }
    float M = red[0]; __syncthreads();
    float ss = 0.f;
    for (int i = t*4; i < NV; i += 1024) {
        float4 v = *(const float4*)(row + i);
        ss += expf(v.x-M) + expf(v.y-M) + expf(v.z-M) + expf(v.w-M);
    }
    red[t] = ss; __syncthreads();
    for (int o = 128; o > 0; o >>= 1) { if (t < o) red[t] += red[t+o]; __syncthreads(); }
    float lse = M + logf(red[0]);
    for (int i = t*4; i < NV; i += 1024) {
        float4 v = *(const float4*)(row + i);
        *(float4*)(row + i) = make_float4(v.x-lse, v.y-lse, v.z-lse, v.w-lse);
    }
}

extern "C" void kernel_launch(void* const* d_in, const int* in_sizes, int n_in,
                              void* d_out, int out_size, void* d_ws, size_t ws_size,
                              hipStream_t stream) {
    const int*   wi   = (const int*)d_in[0];
    const float* lctx = (const float*)d_in[1];
    const float* lhid = (const float*)d_in[2];
    const float* enc  = (const float*)d_in[3];
    const float* emb  = (const float*)d_in[4];
    const float* w_ih = (const float*)d_in[5];
    const float* w_hh = (const float*)d_in[6];
    const float* b_ih = (const float*)d_in[7];
    const float* b_hh = (const float*)d_in[8];
    const float* oW   = (const float*)d_in[9];
    const float* ob   = (const float*)d_in[10];
    float* out = (float*)d_out;
    float* ws  = (float*)d_ws;

    hipLaunchKernelGGL(k_prep,        dim3(64),   dim3(256), 0, stream, wi, lctx, lhid, emb, ws);
    hipLaunchKernelGGL(k_gru_mfma,    dim3(288),  dim3(256), 0, stream, w_ih, w_hh, ws);
    hipLaunchKernelGGL(k_gates,       dim3(256),  dim3(256), 0, stream, ws, b_ih, b_hh, lhid, out, ws);
    hipLaunchKernelGGL(k_attn,        dim3(1024), dim3(256), 0, stream, enc, out, ws);
    hipLaunchKernelGGL(k_attn_reduce, dim3(64),   dim3(256), 0, stream, ws, out, ws);
    hipLaunchKernelGGL(k_logits_mfma, dim3(1000), dim3(256), 0, stream, oW, ws, ws);
    hipLaunchKernelGGL(k_logsoftmax,  dim3(64),   dim3(256), 0, stream, ws, ob, out);
}